// Round 3
// baseline (89.142 us; speedup 1.0000x reference)
//
#include <hip/hip_runtime.h>
#include <math.h>

// Problem constants (from reference)
#define SN   32
#define RR_  16
#define SPK  128
#define NZB  32   // planes per sequence = RR_*2 (one block per (s,r,p) plane)
// PFRAC=0.5, GMAX=1, GMIN=0, TAU=50, H=W=128

// ---------------------------------------------------------------------------
// Structural facts driving the design:
//  1. In the reference scan, step i reads slot time_trace[i-1] and writes slot
//     time_trace[i]; step i+1 reads slot time_trace[i] — always the slot just
//     written. So per pixel the entire 127-step scan is a pure register chain
//     v <- m_i * v (+ spike at that step's pixel), and the final value of any
//     slot r is simply the value at the LAST step that wrote slot r (or the
//     initial state if slot r was never written).
//  2. Only pixels appearing in the event list (<=128, dedup'd to first
//     occurrence) are ever nonzero. Everything else in the 37.7 MB output is
//     exactly zero.
// => One kernel, one block per output plane (s,r,p): zero the plane, locally
//    recompute the cheap register-chain sim tracking only slot r, scatter the
//    owner pixels of polarity p. No workspace, no second kernel, no cross-
//    block hazards (each byte written by exactly one block).
// ---------------------------------------------------------------------------

__global__ __launch_bounds__(256) void te_plane(
    const float* __restrict__ event,       // (SN,128,4): x,y,pol,t
    const int*   __restrict__ time_trace,  // (SN,128) in [0,16)
    const int*   __restrict__ length_,     // (SN,)
    float*       __restrict__ out,         // (SN,16,2,side,side)
    int side)
{
    const int b = blockIdx.x;
    const int s = b / NZB;
    const int c = b % NZB;                 // plane: r = c>>1, p = c&1
    const int r = c >> 1, p = c & 1;
    const int t = threadIdx.x;
    const int plane = side * side;         // 9216 (96) or 5776 (76); %4 == 0

    __shared__ int   ids[SPK];             // packed (pol<<14)|(x<<7)|y
    __shared__ int   uu[SPK];              // first-occurrence (owner) entry
    __shared__ float mm[SPK];              // decay factor for step i (i>=1)
    __shared__ int   tt[SPK];              // time_trace row
    __shared__ float tms[SPK];             // event times

    // ---- start the plane's zero-stores first: HBM writes begin immediately
    float* o = out + (size_t)b * (size_t)plane;
    {
        float4 z4 = make_float4(0.f, 0.f, 0.f, 0.f);
        float4* o4 = (float4*)o;
        const int n4 = plane >> 2;
        for (int k = t; k < n4; k += 256) o4[k] = z4;
    }

    // ---- load this sequence's events / time_trace into LDS
    const float4* ev = (const float4*)(event + (size_t)s * SPK * 4);
    for (int i = t; i < SPK; i += 256) {
        float4 e = ev[i];
        ids[i] = (((int)e.z) << 14) | (((int)e.x) << 7) | ((int)e.y);
        tms[i] = e.w;
        tt[i]  = time_trace[s * SPK + i];
    }
    __syncthreads();

    // ---- dedup (first occurrence) + per-step decay factors
    if (t < SPK) {
        int id = ids[t];
        int u = t;
        for (int j = 0; j < t; ++j) {
            if (ids[j] == id) { u = j; break; }
        }
        uu[t] = u;
        if (t >= 1) {
            // d = t[i-1] - t[i] < 0; double exp -> well-rounded f32 factor
            double d = (double)tms[t - 1] - (double)tms[t];
            mm[t] = (float)exp(d / 50.0);
        }
    }
    __syncthreads();

    // ---- 127-step register-chain sim; track only slot r (last write wins)
    float vr = 0.0f;       // this thread's pixel value in slot r at the end
    bool  own = false;     // does thread t own an in-crop pixel of polarity p?
    int   xo = 0, yo = 0;
    if (t < SPK) {
        const int e   = t;
        const int len = length_[s];
        // initial state: slot 0 holds 0.5 at event-0's pixel (entry 0)
        float v = (tt[0] == 0 && e == 0) ? 0.5f : 0.0f;  // state of slot tt[0]
        vr      = (r == 0     && e == 0) ? 0.5f : 0.0f;  // state of slot r
        if (tt[0] == r) vr = v;   // (same thing; kept for clarity)
        for (int i = 1; i < SPK; ++i) {
            v = v * mm[i];                                // decay
            if ((len >= i) && (uu[i] == e))               // alive spike, owner
                v = v + 0.5f * (1.0f - v);
            if (tt[i] == r) vr = v;                       // last write to slot r
        }
        // owner + polarity + crop test
        if (uu[t] == t) {
            int id = ids[t];
            if (((id >> 14) & 1) == p) {
                int y = id & 127, x = (id >> 7) & 127;
                int off = (128 - side) / 2;
                xo = x - off; yo = y - off;
                own = (xo >= 0 && xo < side && yo >= 0 && yo < side);
            }
        }
    }

    // zero-stores are drained by the waitcnt in __syncthreads -> scatter wins
    __syncthreads();

    if (own) o[xo * side + yo] = vr;
}

extern "C" void kernel_launch(void* const* d_in, const int* in_sizes, int n_in,
                              void* d_out, int out_size, void* d_ws, size_t ws_size,
                              hipStream_t stream) {
    const float* event      = (const float*)d_in[0];
    const int*   time_trace = (const int*)d_in[1];
    const int*   length_    = (const int*)d_in[2];
    float*       out        = (float*)d_out;

    // side from out_size: out = (32,16,2,side,side); test=1 -> 76, else 96
    const int side = (out_size == SN * RR_ * 2 * 76 * 76) ? 76 : 96;

    te_plane<<<SN * NZB, 256, 0, stream>>>(event, time_trace, length_, out, side);
}

// Round 5
// 87.424 us; speedup vs baseline: 1.0196x; 1.0196x over previous
//
#include <hip/hip_runtime.h>
#include <math.h>

// Problem constants (from reference)
#define SN   32
#define RR_  16
#define SPK  128
#define NZB  32   // planes per sequence = RR_*2 (one block per (s,r,p) plane)
// PFRAC=0.5, GMAX=1, GMIN=0, TAU=50, H=W=128

// ---------------------------------------------------------------------------
// Structure: (1) step i of the reference scan reads slot time_trace[i-1],
// which step i-1 just wrote -> per pixel the whole scan is a register chain
// v <- m_i*v (+ spike); final slot r = value at the LAST step writing r (or
// the initial state). (2) only <=128 dedup'd event pixels are ever nonzero.
//
// te_sim (32 blocks) computes the 16x128 sparse state once into d_ws
// (272 KB); te_fill (1024 blocks) only zeroes its (s,r,p) plane + scatters
// <=128 pixels. Every output byte is written by exactly one block.
// ---------------------------------------------------------------------------

// 32 blocks x 128 threads: thread t owns event-entry t.
__global__ __launch_bounds__(128) void te_sim(
    const float* __restrict__ event,       // (SN,128,4): x,y,pol,t
    const int*   __restrict__ time_trace,  // (SN,128) in [0,16)
    const int*   __restrict__ length_,     // (SN,)
    float*       __restrict__ ws_val,      // (SN,16,128) sparse state
    int*         __restrict__ ws_id)       // (SN,128) packed id or -1
{
    const int s = blockIdx.x;
    const int t = threadIdx.x;             // 0..127

    __shared__ int   ids[SPK];             // packed (pol<<14)|(x<<7)|y
    __shared__ int   uu[SPK];              // first-occurrence (owner) entry
    __shared__ float mm[SPK];              // decay factor for step i (i>=1)
    __shared__ int   tt[SPK];              // time_trace row
    __shared__ float tms[SPK];             // event times
    __shared__ float val[RR_ * SPK];       // final sparse state [slot][entry]

    const float4 e = ((const float4*)(event + (size_t)s * SPK * 4))[t];
    ids[t] = (((int)e.z) << 14) | (((int)e.x) << 7) | ((int)e.y);
    tms[t] = e.w;
    tt[t]  = time_trace[s * SPK + t];
    for (int k = t; k < RR_ * SPK; k += 128) val[k] = 0.0f;
    __syncthreads();

    // dedup: u = FIRST j with ids[j]==ids[t]. Downward scan, no break ->
    // fixed trip count, compiler can unroll + pipeline the LDS reads at
    // throughput instead of one latency-exposed read per iteration.
    {
        const int id = ids[t];
        int u = t;
        for (int j = t - 1; j >= 0; --j)
            if (ids[j] == id) u = j;       // last assignment = smallest j
        uu[t] = u;
        if (t >= 1) {
            // d = t[i-1]-t[i] < 0; f64 exp -> correctly rounded f32 factor
            double d = (double)tms[t - 1] - (double)tms[t];
            mm[t] = (float)exp(d / 50.0);
        }
    }
    // initial spike: slot 0, entry 0 (entry 0 is always an owner)
    if (t == 0) val[0 * SPK + 0] = 0.5f;
    __syncthreads();

    // 127-step register chain; last write to each slot wins
    {
        const int len = length_[s];
        float v = (tt[0] == 0 && t == 0) ? 0.5f : 0.0f;  // state of slot tt[0]
        for (int i = 1; i < SPK; ++i) {
            v = v * mm[i];                               // decay
            if ((len >= i) && (uu[i] == t))              // alive spike at owner
                v = v + 0.5f * (1.0f - v);
            val[tt[i] * SPK + t] = v;                    // last write wins
        }
    }
    __syncthreads();

    for (int k = t; k < RR_ * SPK; k += 128)
        ws_val[(size_t)s * RR_ * SPK + k] = val[k];
    ws_id[s * SPK + t] = (uu[t] == t) ? ids[t] : -1;
}

// One block per (s,r,p) plane: zero side^2 floats, scatter <=128 owner pixels.
// No sim work here at all. Every output byte written by exactly one block.
__global__ __launch_bounds__(256) void te_fill(
    const float* __restrict__ ws_val,
    const int*   __restrict__ ws_id,
    float*       __restrict__ out, int side)
{
    const int b = blockIdx.x;
    const int s = b / NZB;
    const int c = b % NZB;                 // plane: r = c>>1, p = c&1
    const int r = c >> 1, p = c & 1;
    const int t = threadIdx.x;
    const int plane = side * side;         // 9216 (96) / 5776 (76); %4 == 0

    float* o = out + (size_t)b * (size_t)plane;

    // issue the scatter-candidate loads first so they overlap the zero-stores
    int   id = -1;
    float v  = 0.0f;
    if (t < SPK) {
        id = ws_id[s * SPK + t];
        if (id >= 0 && ((id >> 14) & 1) == p)
            v = ws_val[((size_t)s * RR_ + r) * SPK + t];
        else
            id = -1;
    }

    float4  z4 = make_float4(0.f, 0.f, 0.f, 0.f);
    float4* o4 = (float4*)o;
    const int n4 = plane >> 2;
    for (int k = t; k < n4; k += 256) o4[k] = z4;

    __syncthreads();   // drains the zero-stores; scatter below must win

    if (id >= 0) {
        int y = id & 127, x = (id >> 7) & 127;
        int off = (128 - side) / 2;
        int xo = x - off, yo = y - off;
        if (xo >= 0 && xo < side && yo >= 0 && yo < side)
            o[xo * side + yo] = v;
    }
}

extern "C" void kernel_launch(void* const* d_in, const int* in_sizes, int n_in,
                              void* d_out, int out_size, void* d_ws, size_t ws_size,
                              hipStream_t stream) {
    const float* event      = (const float*)d_in[0];
    const int*   time_trace = (const int*)d_in[1];
    const int*   length_    = (const int*)d_in[2];
    float*       out        = (float*)d_out;

    // side from out_size: out = (32,16,2,side,side); test=1 -> 76, else 96
    const int side = (out_size == SN * RR_ * 2 * 76 * 76) ? 76 : 96;

    float* ws_val = (float*)d_ws;
    int*   ws_id  = (int*)((char*)d_ws + (size_t)SN * RR_ * SPK * sizeof(float));

    te_sim <<<SN,       128, 0, stream>>>(event, time_trace, length_,
                                          ws_val, ws_id);
    te_fill<<<SN * NZB, 256, 0, stream>>>(ws_val, ws_id, out, side);
}